// Round 1
// baseline (137.418 us; speedup 1.0000x reference)
//
#include <hip/hip_runtime.h>

#define B_   512
#define F_   2048
#define K_   64
#define D_   16
#define N_   (K_*D_)    // 1024
#define OUTW (F_+K_)    // 2112

// ---------------- x copy: out[b][0:2048] = x[b][:] ----------------
__global__ __launch_bounds__(256) void copy_x_kernel(const float* __restrict__ x,
                                                     float* __restrict__ out) {
    // 512*2048 floats = 262144 float4
    const int total = (B_ * F_) / 4;
    for (int i = blockIdx.x * blockDim.x + threadIdx.x; i < total; i += gridDim.x * blockDim.x) {
        int b = i >> 9;          // 512 float4 per row
        int c = i & 511;
        float4 v = ((const float4*)x)[i];
        // out row stride 2112 floats = 528 float4
        ((float4*)out)[b * (OUTW/4) + c] = v;
    }
}

// ---------------- GEMM: act[k][b][d] += x[b][f] * W[f][k*16+d] ----------------
// tiles: BM=64 (b), BN=64 (n=k*16+d), BK=16 (f). split-K=4 chunks of 512.
#define BM 64
#define BN 64
#define BK 16
#define KSPLIT 4
#define KCH (F_/KSPLIT)   // 512

__global__ __launch_bounds__(256) void gemm_kernel(const float* __restrict__ x,
                                                   const float* __restrict__ w,
                                                   float* __restrict__ act) {
    __shared__ float xs[BK][68];   // transposed x tile [f][b], padded (272B row = 16B-aligned)
    __shared__ float ws[BK][BN];   // w tile [f][n]

    const int bm0 = blockIdx.x * BM;   // 8 tiles
    const int bn0 = blockIdx.y * BN;   // 16 tiles
    const int f0  = blockIdx.z * KCH;  // 4 chunks

    const int tid = threadIdx.x;
    const int tx = tid & 15;     // n micro ->  tx*4 .. tx*4+3
    const int ty = tid >> 4;     // m micro ->  ty*4 .. ty*4+3

    // staging index assignments
    const int lm = tid >> 2;          // 0..63 : b row of x tile
    const int lf = (tid & 3) * 4;     // 0,4,8,12 : f group
    const int wf = tid >> 4;          // 0..15 : f row of w tile
    const int wn = (tid & 15) * 4;    // n group

    float acc[4][4] = {};

    for (int fs = 0; fs < KCH; fs += BK) {
        const int f = f0 + fs;
        const float4 xa = *(const float4*)(x + (size_t)(bm0 + lm) * F_ + f + lf);
        const float4 wa = *(const float4*)(w + (size_t)(f + wf) * N_ + bn0 + wn);
        __syncthreads();   // previous iteration's reads done before overwrite
        xs[lf + 0][lm] = xa.x;
        xs[lf + 1][lm] = xa.y;
        xs[lf + 2][lm] = xa.z;
        xs[lf + 3][lm] = xa.w;
        *(float4*)&ws[wf][wn] = wa;
        __syncthreads();
        #pragma unroll
        for (int kk = 0; kk < BK; ++kk) {
            const float4 a4 = *(const float4*)&xs[kk][ty * 4];
            const float4 b4 = *(const float4*)&ws[kk][tx * 4];
            const float a[4] = {a4.x, a4.y, a4.z, a4.w};
            const float b[4] = {b4.x, b4.y, b4.z, b4.w};
            #pragma unroll
            for (int i = 0; i < 4; ++i)
                #pragma unroll
                for (int j = 0; j < 4; ++j)
                    acc[i][j] = fmaf(a[i], b[j], acc[i][j]);
        }
    }

    // epilogue: atomic accumulate into act[k][b][d]  (split-K partials)
    #pragma unroll
    for (int i = 0; i < 4; ++i) {
        const int b = bm0 + ty * 4 + i;
        #pragma unroll
        for (int j = 0; j < 4; ++j) {
            const int n = bn0 + tx * 4 + j;
            const int k = n >> 4;
            const int d = n & 15;
            atomicAdd(&act[((size_t)k * B_ + b) * D_ + d], acc[i][j]);
        }
    }
}

// ---------------- pairwise: feats[b][k] = sum_b2 exp(-sum_d |act[k][b][d]-act[k][b2][d]|) ----------------
__global__ __launch_bounds__(256) void pairwise_kernel(const float* __restrict__ act,
                                                       float* __restrict__ out) {
    __shared__ float s_act[B_ * D_];   // 32 KB: whole k-slice [b][d]
    __shared__ float red[4][64];

    const int bt = blockIdx.x;    // 8 b-tiles of 64
    const int k  = blockIdx.y;    // 64
    const int tid  = threadIdx.x;
    const int lane = tid & 63;
    const int wave = tid >> 6;

    // stage k-slice (8192 floats = 2048 float4, 8 per thread, coalesced)
    const float4* src = (const float4*)(act + (size_t)k * B_ * D_);
    #pragma unroll
    for (int i = tid; i < (B_ * D_) / 4; i += 256)
        ((float4*)s_act)[i] = src[i];
    __syncthreads();

    // own row
    const int b = bt * 64 + lane;
    float a[D_];
    #pragma unroll
    for (int d = 0; d < D_; ++d) a[d] = s_act[b * D_ + d];

    // each wave covers 128 b2 values
    float p = 0.0f;
    const int b2lo = wave * 128;
    #pragma unroll 2
    for (int b2 = b2lo; b2 < b2lo + 128; ++b2) {
        const float* v = &s_act[b2 * D_];
        float dist = 0.0f;
        #pragma unroll
        for (int d = 0; d < D_; ++d) dist += fabsf(a[d] - v[d]);
        p += __expf(-dist);
    }

    red[wave][lane] = p;
    __syncthreads();
    if (wave == 0) {
        const float total = red[0][lane] + red[1][lane] + red[2][lane] + red[3][lane];
        out[(size_t)b * OUTW + F_ + k] = total;
    }
}

extern "C" void kernel_launch(void* const* d_in, const int* in_sizes, int n_in,
                              void* d_out, int out_size, void* d_ws, size_t ws_size,
                              hipStream_t stream) {
    const float* x = (const float*)d_in[0];
    const float* w = (const float*)d_in[1];
    float* out = (float*)d_out;
    float* act = (float*)d_ws;   // 64*512*16 floats = 2 MB, layout [k][b][d]

    hipMemsetAsync(act, 0, (size_t)K_ * B_ * D_ * sizeof(float), stream);
    copy_x_kernel<<<256, 256, 0, stream>>>(x, out);
    gemm_kernel<<<dim3(8, 16, KSPLIT), 256, 0, stream>>>(x, w, act);
    pairwise_kernel<<<dim3(8, K_), 256, 0, stream>>>(act, out);
}

// Round 2
// 107.747 us; speedup vs baseline: 1.2754x; 1.2754x over previous
//
#include <hip/hip_runtime.h>

#define B_   512
#define F_   2048
#define K_   64
#define D_   16
#define N_   1024
#define OUTW (F_+K_)    // 2112

typedef __attribute__((ext_vector_type(8))) short short8;
typedef __attribute__((ext_vector_type(4))) float f32x4;

__device__ __forceinline__ ushort f2bf(float f) {
    union { float f; unsigned u; } un; un.f = f;
    unsigned u = un.u;
    u += 0x7FFF + ((u >> 16) & 1);   // RNE
    return (ushort)(u >> 16);
}

// ---- fused: out[b][0:2048] = x  AND  xb = bf16(x) ----
__global__ __launch_bounds__(256) void convert_x_kernel(const float* __restrict__ x,
                                                        float* __restrict__ out,
                                                        ushort* __restrict__ xb) {
    const int i = blockIdx.x * 256 + threadIdx.x;     // 262144 float4's
    float4 v = ((const float4*)x)[i];
    const int b = i >> 9, c = i & 511;
    ((float4*)out)[b * (OUTW / 4) + c] = v;
    ushort4 u = make_ushort4(f2bf(v.x), f2bf(v.y), f2bf(v.z), f2bf(v.w));
    ((ushort4*)xb)[i] = u;
}

// ---- Wt[n][f] = bf16(W[f][n]) : LDS-tiled transpose ----
__global__ __launch_bounds__(256) void convert_wt_kernel(const float* __restrict__ w,
                                                         ushort* __restrict__ wt) {
    __shared__ float t[32][33];
    const int f0 = blockIdx.x * 32;    // 64
    const int n0 = blockIdx.y * 32;    // 32
    const int tid = threadIdx.x;
    const int r = tid >> 3;            // 0..31
    const int c4 = (tid & 7) * 4;      // 0..28
    float4 v = *(const float4*)(w + (size_t)(f0 + r) * N_ + n0 + c4);
    t[r][c4 + 0] = v.x; t[r][c4 + 1] = v.y; t[r][c4 + 2] = v.z; t[r][c4 + 3] = v.w;
    __syncthreads();
    ushort4 u = make_ushort4(f2bf(t[c4 + 0][r]), f2bf(t[c4 + 1][r]),
                             f2bf(t[c4 + 2][r]), f2bf(t[c4 + 3][r]));
    *(ushort4*)(wt + (size_t)(n0 + r) * F_ + f0 + c4) = u;
}

// ---- MFMA GEMM: act[k][b][d] += x[b][f] * W[f][k*16+d] ----
// A = xb [512][2048] bf16, B^T = wt [1024][2048] bf16. 64x64 tile, 4 waves 2x2,
// split-K=4, fragments straight from global (L2-resident), no LDS.
#define KSPLIT 4
#define KCH (F_/KSPLIT)   // 512

__global__ __launch_bounds__(256) void gemm_mfma_kernel(const ushort* __restrict__ xb,
                                                        const ushort* __restrict__ wt,
                                                        float* __restrict__ act) {
    const int bm0 = blockIdx.x * 64;   // 8
    const int bn0 = blockIdx.y * 64;   // 16
    const int f0  = blockIdx.z * KCH;  // 4

    const int tid = threadIdx.x;
    const int l   = tid & 63;
    const int w   = tid >> 6;
    const int mw  = (w >> 1) * 32;
    const int nw  = (w & 1) * 32;
    const int lr  = l & 15;            // row-within-16 (A) / col (B,D)
    const int lk  = (l >> 4) * 8;      // k-group

    const ushort* pa0 = xb + (size_t)(bm0 + mw + lr) * F_ + f0 + lk;
    const ushort* pa1 = pa0 + 16 * F_;
    const ushort* pb0 = wt + (size_t)(bn0 + nw + lr) * F_ + f0 + lk;
    const ushort* pb1 = pb0 + 16 * F_;

    f32x4 acc00 = {}, acc01 = {}, acc10 = {}, acc11 = {};

    #pragma unroll 4
    for (int kk = 0; kk < KCH; kk += 32) {
        short8 a0 = *(const short8*)(pa0 + kk);
        short8 a1 = *(const short8*)(pa1 + kk);
        short8 b0 = *(const short8*)(pb0 + kk);
        short8 b1 = *(const short8*)(pb1 + kk);
        acc00 = __builtin_amdgcn_mfma_f32_16x16x32_bf16(a0, b0, acc00, 0, 0, 0);
        acc01 = __builtin_amdgcn_mfma_f32_16x16x32_bf16(a0, b1, acc01, 0, 0, 0);
        acc10 = __builtin_amdgcn_mfma_f32_16x16x32_bf16(a1, b0, acc10, 0, 0, 0);
        acc11 = __builtin_amdgcn_mfma_f32_16x16x32_bf16(a1, b1, acc11, 0, 0, 0);
    }

    // D layout: col = l&15 (n), row = (l>>4)*4 + reg (m)
    const int mbase = bm0 + mw + (l >> 4) * 4;
    #pragma unroll
    for (int j = 0; j < 2; ++j) {
        const int n = bn0 + nw + j * 16 + lr;
        const int k = n >> 4, d = n & 15;
        float* dst = act + (size_t)k * (B_ * D_) + d;
        const f32x4 c0 = j ? acc01 : acc00;
        const f32x4 c1 = j ? acc11 : acc10;
        #pragma unroll
        for (int r = 0; r < 4; ++r) {
            atomicAdd(dst + (size_t)(mbase + r) * D_,      c0[r]);
            atomicAdd(dst + (size_t)(mbase + 16 + r) * D_, c1[r]);
        }
    }
}

// ---- pairwise: feats[b][k] = sum_b2 exp(-sum_d |act[k][b][d]-act[k][b2][d]|) ----
__global__ __launch_bounds__(256) void pairwise_kernel(const float* __restrict__ act,
                                                       float* __restrict__ out) {
    __shared__ float s_act[B_ * D_];   // 32 KB
    __shared__ float red[4][64];

    const int bt = blockIdx.x;    // 8
    const int k  = blockIdx.y;    // 64
    const int tid  = threadIdx.x;
    const int lane = tid & 63;
    const int wave = tid >> 6;

    const float4* src = (const float4*)(act + (size_t)k * B_ * D_);
    #pragma unroll
    for (int i = tid; i < (B_ * D_) / 4; i += 256)
        ((float4*)s_act)[i] = src[i];
    __syncthreads();

    const int b = bt * 64 + lane;
    float a[D_];
    #pragma unroll
    for (int d = 0; d < D_; ++d) a[d] = s_act[b * D_ + d];

    float p = 0.0f;
    const int b2lo = wave * 128;
    #pragma unroll 4
    for (int b2 = b2lo; b2 < b2lo + 128; ++b2) {
        const float* v = &s_act[b2 * D_];
        float dist = 0.0f;
        #pragma unroll
        for (int d = 0; d < D_; ++d) dist += fabsf(a[d] - v[d]);
        p += __expf(-dist);
    }

    red[wave][lane] = p;
    __syncthreads();
    if (wave == 0) {
        const float total = red[0][lane] + red[1][lane] + red[2][lane] + red[3][lane];
        out[(size_t)b * OUTW + F_ + k] = total;
    }
}

extern "C" void kernel_launch(void* const* d_in, const int* in_sizes, int n_in,
                              void* d_out, int out_size, void* d_ws, size_t ws_size,
                              hipStream_t stream) {
    const float* x = (const float*)d_in[0];
    const float* wsrc = (const float*)d_in[1];
    float* out = (float*)d_out;

    // ws layout: xb bf16 [512][2048] (2MB) | wt bf16 [1024][2048] (4MB) | act f32 [64][512][16] (2MB)
    ushort* xb  = (ushort*)d_ws;
    ushort* wt  = (ushort*)((char*)d_ws + (size_t)2 * 1024 * 1024);
    float*  act = (float*)((char*)d_ws + (size_t)6 * 1024 * 1024);

    hipMemsetAsync(act, 0, (size_t)K_ * B_ * D_ * sizeof(float), stream);
    convert_x_kernel<<<1024, 256, 0, stream>>>(x, out, xb);
    convert_wt_kernel<<<dim3(64, 32), 256, 0, stream>>>(wsrc, wt);
    gemm_mfma_kernel<<<dim3(8, 16, KSPLIT), 256, 0, stream>>>(xb, wt, act);
    pairwise_kernel<<<dim3(8, K_), 256, 0, stream>>>(act, out);
}